// Round 5
// baseline (135.881 us; speedup 1.0000x reference)
//
#include <hip/hip_runtime.h>
#include <math.h>
#include <stdint.h>

#define NBATCH 16384
#define MB 16
#define NT 256
#define NBLOCKS (NBATCH/MB)
#define WT_BYTE_OFF 2560

typedef float  f32x4 __attribute__((ext_vector_type(4)));
typedef short  s16x8 __attribute__((ext_vector_type(8)));

// ================= compile-time CG (double precision, mirrors validated device math) ==========
constexpr double cfact(int n){ double r=1.0; for(int i=2;i<=n;++i) r*=(double)i; return r; }
constexpr double csqrt_(double x){
  if (x<=0.0) return 0.0;
  double m=x, k=1.0;
  while (m>1.0) { m*=0.25; k*=2.0; }
  while (m<0.25){ m*=4.0;  k*=0.5; }
  double g=0.7;
  for(int i=0;i<14;++i) g = 0.5*(g + m/g);
  return g*k;
}
constexpr double su2d(int j1,int j2,int j3,int m1,int m2,int m3){
  if (m1+m2 != m3) return 0.0;
  double pref = csqrt_((double)(2*j3+1)*cfact(j1+j2-j3)*cfact(j1-j2+j3)*cfact(-j1+j2+j3)/cfact(j1+j2+j3+1));
  pref *= csqrt_(cfact(j3+m3)*cfact(j3-m3)*cfact(j1-m1)*cfact(j1+m1)*cfact(j2-m2)*cfact(j2+m2));
  double s=0.0;
  for (int v=0; v<=j1+j2-j3; ++v){
    int a=j1+j2-j3-v, b=j1-m1-v, c=j2+m2-v, d=j3-j2+m1+v, e=j3-j1-m2+v;
    if (a<0||b<0||c<0||d<0||e<0) continue;
    double t = 1.0/(cfact(v)*cfact(a)*cfact(b)*cfact(c)*cfact(d)*cfact(e));
    s += (v&1)? -t : t;
  }
  return pref*s;
}
struct C2 { double re, im; };
constexpr C2 qvald(int l,int r,int c){
  int m = r - l;
  const double is2 = 0.70710678118654752440;
  double br=0.0, bi=0.0;
  if (m<0){ if (c==l-m) br=is2; else if (c==l+m) bi=-is2; }
  else if (m==0){ if (c==l) br=1.0; }
  else { double sg=(m&1)?-1.0:1.0; if (c==l+m) br=sg*is2; else if (c==l-m) bi=sg*is2; }
  if (l==1){ double nr=bi, ni=-br; br=nr; bi=ni; }   // *(-i)
  else if (l==2){ br=-br; bi=-bi; }                  // *(-i)^2
  return C2{br,bi};
}
constexpr int HP_L1[15]={0,1,2,0,1,1,1,2,2,0,1,1,2,2,2};
constexpr int HP_L2[15]={0,1,2,1,0,1,2,1,2,2,1,2,0,1,2};
constexpr int HP_L3[15]={0,0,0,1,1,1,1,1,1,2,2,2,2,2,2};
constexpr int HP_CGOFF[15]={0,1,10,35,44,53,80,125,170,245,270,315,390,415,490};
constexpr int HP_TSTART[15]={0,1,4,9,12,21,30,39,54,69,74,89,104,129,154};
constexpr int HP_YOFF[15]={0,1,4,1,0,1,4,1,4,4,1,4,0,1,4};

struct CGT { float v[616]; };
constexpr CGT make_cg_part(int p0, int p1){
  CGT T{};
  for (int z=0; z<616; ++z) T.v[z]=0.f;
  for (int p=p0; p<p1; ++p){
    int l1=HP_L1[p], l2=HP_L2[p], l3=HP_L3[p];
    int d1=2*l1+1, d2=2*l2+1, d3=2*l3+1;
    double su[5][5]={};
    for (int i=0;i<d1;++i) for (int k=0;k<d2;++k){
      int n = i+k-l1-l2+l3;
      su[i][k] = (n>=0 && n<d3) ? su2d(l1,l2,l3, i-l1, k-l2, n-l3) : 0.0;
    }
    for (int i1=0;i1<d1;++i1) for (int i2=0;i2<d2;++i2) for (int i3=0;i3<d3;++i3){
      double val=0.0;
      for (int i=0;i<d1;++i) for (int k=0;k<d2;++k){
        int n = i+k-l1-l2+l3;
        if (n<0||n>=d3) continue;
        double c = su[i][k];
        if (c==0.0) continue;
        C2 q1=qvald(l1,i,i1), q2=qvald(l2,k,i2), q3=qvald(l3,n,i3);
        double ar = q1.re*q2.re - q1.im*q2.im;
        double ai = q1.re*q2.im + q1.im*q2.re;
        val += (ar*q3.re + ai*q3.im)*c;    // Re[(q1*q2)*conj(q3)] * su2
      }
      T.v[HP_CGOFF[p] + (i1*d2+i2)*d3 + i3] = (float)val;
    }
  }
  return T;
}
constexpr CGT CG_A = make_cg_part(0,8);
constexpr CGT CG_B = make_cg_part(8,12);
constexpr CGT CG_D = make_cg_part(12,15);
constexpr CGT cg_merge(){
  CGT T{};
  for (int i=0;i<616;++i) T.v[i] = CG_A.v[i] + CG_B.v[i] + CG_D.v[i];
  return T;
}
__device__ __constant__ const CGT CGC = cg_merge();

// packed T descriptor per e: base(10) | d2<<10 (3) | stride<<13 (3) | yoff<<16 (3)
constexpr uint32_t make_td(int e){
  if (e>=179) return 0u;
  int p=0; while (p<14 && e>=HP_TSTART[p+1]) ++p;
  int r = e - HP_TSTART[p];
  int d2 = 2*HP_L2[p]+1, d3 = 2*HP_L3[p]+1;
  int i1 = r/d3, j3 = r - (r/d3)*d3;
  int base = HP_CGOFF[p] + i1*d2*d3 + j3;
  return (uint32_t)base | ((uint32_t)d2<<10) | ((uint32_t)d3<<13) | ((uint32_t)HP_YOFF[p]<<16);
}
struct TDT { uint32_t v[192]; };
constexpr TDT make_tdt(){ TDT t{}; for(int e=0;e<192;++e) t.v[e]=make_td(e); return t; }
__device__ __constant__ const TDT TDC = make_tdt();

// inverse x-permute: output slot o -> source column c (0xFFFF = zero pad)
// layout of CMC.v is [64 chunks][8 slots] -> one uint4 load per chunk
constexpr uint16_t cmap1(int o){
  if (o<128) return (uint16_t)o;
  if (o<320){ int s=o-128; int i1=s>>6; int u=s&63; return (uint16_t)(128 + u*3 + i1); }
  if (o<480){ int s=o-320; int i1=s>>5; int u=s&31; return (uint16_t)(320 + u*5 + i1); }
  return (uint16_t)0xFFFF;
}
struct CMT { uint16_t v[512]; };
constexpr CMT make_cm(){ CMT t{}; for(int o=0;o<512;++o) t.v[o]=cmap1(o); return t; }
__device__ __constant__ const CMT CMC = make_cm();

// ---------------- weight segments (validated) ----------------
__device__ const int   SEG_WB[15] = {0,16384,24576, 28672,36864,40960,45056,49152,51200,
                                     53248,57344,59392,61440,62464,63488};
__device__ const int   SEG_SH[15] = {7,6,5, 7,6,6,6,5,5, 7,6,6,5,5,5};
__device__ const int   SEG_U0[15] = {0,128,192, 0,128,192,256,320,352, 0,128,192,256,288,320};
__device__ const int   SEG_G[15]  = {0,0,0, 1,1,1,1,1,1, 2,2,2,2,2,2};
__device__ const float SEG_SC[3]  = {0.066815310478f, 0.051031036308f, 0.053300179089f};

// ---------------- bf16 helpers ----------------
__device__ __forceinline__ uint32_t f2bf(float f){
  uint32_t u = __float_as_uint(f);
  return (u + 0x7fffu + ((u>>16)&1u)) >> 16;   // RNE
}

// ================= pack_w: weight pack only (64512 threads = 252 blocks) ==================
__global__ __launch_bounds__(NT) void pack_w(const float* __restrict__ W0, const float* __restrict__ W1,
                                             const float* __restrict__ W2, float* __restrict__ ws)
{
  int t = blockIdx.x*NT + threadIdx.x;
  uint16_t* wt = (uint16_t*)((char*)ws + WT_BYTE_OFF);
  int j = 0;
  while (j < 14 && t >= SEG_WB[j+1]) ++j;
  int idx = t - SEG_WB[j];
  int sh = SEG_SH[j];
  int v  = idx >> sh, u1 = idx & ((1<<sh)-1);
  int g  = SEG_G[j];
  int N  = (g==0)?128:(g==1)?64:32;
  const float* Wsrc = (g==0)?W0:(g==1)?W1:W2;
  wt[t] = (uint16_t)f2bf(Wsrc[(SEG_U0[j]+u1)*N + v] * SEG_SC[g]);
}

// ---------------- per-group compile-time metadata ----------------
template<int G> struct GM;
template<> struct GM<0>{
  static constexpr int NS=3, D3=1, NMT=2, NI3=1;
  static constexpr int MUL[3]={128,64,32};
  static constexpr int D1[3] ={1,3,5};
  static constexpr int XB[3] ={0,128,320};
  static constexpr int TS[3] ={0,1,4};
  static constexpr int WB[3] ={0,16384,24576};
};
template<> struct GM<1>{
  static constexpr int NS=6, D3=3, NMT=1, NI3=3;
  static constexpr int MUL[6]={128,64,64,64,32,32};
  static constexpr int D1[6] ={1,3,3,3,5,5};
  static constexpr int XB[6] ={0,128,128,128,320,320};
  static constexpr int TS[6] ={9,12,21,30,39,54};
  static constexpr int WB[6] ={28672,36864,40960,45056,49152,51200};
};
template<> struct GM<2>{
  static constexpr int NS=6, D3=5, NMT=1, NI3=3;
  static constexpr int MUL[6]={128,64,64,32,32,32};
  static constexpr int D1[6] ={1,3,3,5,5,5};
  static constexpr int XB[6] ={0,128,128,320,320,320};
  static constexpr int TS[6] ={69,74,89,104,129,154};
  static constexpr int WB[6] ={53248,57344,59392,61440,62464,63488};
};

// one segment: A=Wt (m=v), B=xp (n=batch), K=mul; T-contract into acc
template<int G, int S, int NMT, int NI3>
__device__ __forceinline__ void do_seg(const short* __restrict__ wt,
                                       const uint16_t* __restrict__ xp,
                                       const float* __restrict__ Tsh,
                                       f32x4 (&acc)[NMT][NI3],
                                       int ln, int koct, int mt0, int i3base, int ni3)
{
  using M = GM<G>;
  constexpr int MUL = M::MUL[S];
  constexpr int KS  = MUL >> 5;
  constexpr int D1  = M::D1[S];

  s16x8 Af[NMT][KS];
  #pragma unroll
  for (int mt = 0; mt < NMT; ++mt)
    #pragma unroll
    for (int kk = 0; kk < KS; ++kk)
      Af[mt][kk] = *(const s16x8*)(wt + M::WB[S] + ((mt0+mt)*16 + ln)*MUL + kk*32 + koct);

  const int swz = (ln & 7) << 4;
  const int koct2 = koct*2;
  const char* xrow = (const char*)xp + ln*1024;

  #pragma unroll
  for (int i1 = 0; i1 < D1; ++i1){
    s16x8 Bf[KS];
    #pragma unroll
    for (int kk = 0; kk < KS; ++kk){
      const int cb = (M::XB[S] + i1*MUL + kk*32)*2 + koct2;
      Bf[kk] = *(const s16x8*)(xrow + (cb ^ swz));
    }
    f32x4 D[NMT];
    #pragma unroll
    for (int mt = 0; mt < NMT; ++mt){
      D[mt] = (f32x4){0.f,0.f,0.f,0.f};
      #pragma unroll
      for (int kk = 0; kk < KS; ++kk)
        D[mt] = __builtin_amdgcn_mfma_f32_16x16x32_bf16(Af[mt][kk], Bf[kk], D[mt], 0, 0, 0);
    }
    #pragma unroll
    for (int j = 0; j < NI3; ++j){
      if (j < ni3){
        const int e = M::TS[S] + i1*M::D3 + i3base + j;
        const float tv = Tsh[e*16 + ln];
        #pragma unroll
        for (int mt = 0; mt < NMT; ++mt){
          acc[mt][j][0] += tv*D[mt][0];
          acc[mt][j][1] += tv*D[mt][1];
          acc[mt][j][2] += tv*D[mt][2];
          acc[mt][j][3] += tv*D[mt][3];
        }
      }
    }
  }
}

template<int G>
__device__ __forceinline__ void run_group(const short* __restrict__ wt,
                                          float* __restrict__ out, int b0, int tid,
                                          const float* __restrict__ Tsh,
                                          const uint16_t* __restrict__ xp)
{
  using M = GM<G>;
  const int lane = tid & 63, w = tid >> 6;
  const int ln   = lane & 15;          // A: m-index / B: n-index / D: col (=batch)
  const int koct = (lane >> 4) * 8;    // k-octet
  constexpr int NMT = M::NMT, NI3 = M::NI3;

  int mt0, i3base, ni3;
  if constexpr (G == 0){ mt0 = 2*w; i3base = 0; ni3 = 1; }
  else if constexpr (G == 1){ mt0 = w; i3base = 0; ni3 = 3; }
  else { mt0 = w >> 1; i3base = (w & 1)*3; ni3 = (w & 1) ? 2 : 3; }

  f32x4 acc[NMT][NI3];
  #pragma unroll
  for (int a = 0; a < NMT; ++a)
    #pragma unroll
    for (int b = 0; b < NI3; ++b) acc[a][b] = (f32x4){0.f,0.f,0.f,0.f};

  do_seg<G,0,NMT,NI3>(wt, xp, Tsh, acc, ln, koct, mt0, i3base, ni3);
  do_seg<G,1,NMT,NI3>(wt, xp, Tsh, acc, ln, koct, mt0, i3base, ni3);
  do_seg<G,2,NMT,NI3>(wt, xp, Tsh, acc, ln, koct, mt0, i3base, ni3);
  if constexpr (M::NS > 3){
    do_seg<G,(M::NS>3)?3:0,NMT,NI3>(wt, xp, Tsh, acc, ln, koct, mt0, i3base, ni3);
    do_seg<G,(M::NS>4)?4:0,NMT,NI3>(wt, xp, Tsh, acc, ln, koct, mt0, i3base, ni3);
    do_seg<G,(M::NS>5)?5:0,NMT,NI3>(wt, xp, Tsh, acc, ln, koct, mt0, i3base, ni3);
  }

  // ---- stores: D col=lane&15=batch, rows=(lane>>4)*4+r = v (r3-verified) ----
  const int rq = (lane >> 4) * 4;
  float* orow = out + (size_t)(b0 + ln)*480;
  if constexpr (G == 0){
    #pragma unroll
    for (int mt = 0; mt < NMT; ++mt){
      const int vb = (mt0+mt)*16 + rq;
      float4 st = make_float4(acc[mt][0][0], acc[mt][0][1], acc[mt][0][2], acc[mt][0][3]);
      *(float4*)(orow + vb) = st;            // cols v..v+3, 16B aligned
    }
  } else if constexpr (G == 1){
    const int vb = mt0*16 + rq;
    float buf[12];
    #pragma unroll
    for (int r = 0; r < 4; ++r)
      #pragma unroll
      for (int j = 0; j < 3; ++j) buf[r*3+j] = acc[0][j][r];
    float* p = orow + 128 + vb*3;            // 128+12k -> 16B aligned
    *(float4*)(p)   = make_float4(buf[0],buf[1],buf[2],buf[3]);
    *(float4*)(p+4) = make_float4(buf[4],buf[5],buf[6],buf[7]);
    *(float4*)(p+8) = make_float4(buf[8],buf[9],buf[10],buf[11]);
  } else {
    const int vb = mt0*16 + rq;
    #pragma unroll
    for (int r = 0; r < 4; ++r)
      #pragma unroll
      for (int j = 0; j < 3; ++j)
        if (j < ni3)
          orow[320 + (vb+r)*5 + i3base + j] = acc[0][j][r];
  }
}

// ====== fused: dest-major gather (global->reg->swizzled xp, conflict-free b128 writes) ======
__global__ __launch_bounds__(NT) void tp_fused(const float* __restrict__ x,
                                               const float* __restrict__ y,
                                               const float* __restrict__ ws,
                                               float* __restrict__ out)
{
  __shared__ __align__(16) uint16_t xp[MB*512];      // 16384 B  swizzled permuted rows
  __shared__ __align__(16) float    Tshf[192*16];    // 12288 B  T[e][b] f32
  // total 28672 B

  const int tid = threadIdx.x;
  const int b0 = blockIdx.x * MB;
  const short* wt = (const short*)((const char*)ws + WT_BYTE_OFF);

  // ---- phase 1a: dest-major permute-gather. Thread owns one 16B dest chunk per iter:
  //   1x uint4 map load + 8 scalar x loads (L1: row is 1920B contiguous) + 1 ds_write_b128.
  //   Dest byte: b*1024 + ((c16*16) ^ ((b&7)<<4))  — conflict-free (r2-verified), matches reader.
  #pragma unroll
  for (int it = 0; it < 4; ++it){
    const int chunk = it*NT + tid;                 // 0..1023
    const int b = chunk >> 6, c16 = chunk & 63;    // wave = one batch row
    const uint4 m4 = ((const uint4*)CMC.v)[c16];
    const uint16_t* mp = (const uint16_t*)&m4;
    const float* xr = x + (size_t)(b0 + b)*480;
    uint16_t vals[8];
    #pragma unroll
    for (int jj = 0; jj < 8; ++jj){
      const uint16_t c = mp[jj];
      vals[jj] = (c == 0xFFFFu) ? (uint16_t)0 : (uint16_t)f2bf(xr[c]);
    }
    *(uint4*)((char*)xp + b*1024 + ((c16*16) ^ ((b&7)<<4))) = *(const uint4*)vals;
  }

  // ---- phase 1b: T[e][b] straight from global y (576B window, L1-broadcast) ----
  if (tid < 179){
    const uint32_t td = TDC.v[tid];
    const int base = td & 1023, d2 = (td>>10)&7, str = (td>>13)&7, yoff = (td>>16)&7;
    const float* yb = y + (size_t)b0*9 + yoff;
    float tv[16];
    #pragma unroll
    for (int b = 0; b < 16; ++b){
      float t = 0.f;
      for (int i2 = 0; i2 < d2; ++i2) t += CGC.v[base + i2*str] * yb[b*9 + i2];
      tv[b] = t;
    }
    float4* dst = (float4*)&Tshf[tid*16];
    dst[0] = make_float4(tv[0], tv[1], tv[2], tv[3]);
    dst[1] = make_float4(tv[4], tv[5], tv[6], tv[7]);
    dst[2] = make_float4(tv[8], tv[9], tv[10],tv[11]);
    dst[3] = make_float4(tv[12],tv[13],tv[14],tv[15]);
  }
  __syncthreads();

  // ---- phase 2: 3 groups, no further barriers (xp/Tshf read-only from here) ----
  run_group<0>(wt, out, b0, tid, Tshf, xp);
  run_group<1>(wt, out, b0, tid, Tshf, xp);
  run_group<2>(wt, out, b0, tid, Tshf, xp);
}

extern "C" void kernel_launch(void* const* d_in, const int* in_sizes, int n_in,
                              void* d_out, int out_size, void* d_ws, size_t ws_size,
                              hipStream_t stream)
{
  const float* x  = (const float*)d_in[0];
  const float* y  = (const float*)d_in[1];
  const float* W0 = (const float*)d_in[2];
  const float* W1 = (const float*)d_in[3];
  const float* W2 = (const float*)d_in[4];
  float* out = (float*)d_out;
  float* ws  = (float*)d_ws;   // bf16 Wt at +2560 (CG is compile-time)

  hipLaunchKernelGGL(pack_w, dim3(252), dim3(NT), 0, stream, W0, W1, W2, ws);
  hipLaunchKernelGGL(tp_fused, dim3(NBLOCKS), dim3(NT), 0, stream, x, y, ws, out);
}

// Round 6
// 120.559 us; speedup vs baseline: 1.1271x; 1.1271x over previous
//
#include <hip/hip_runtime.h>
#include <math.h>
#include <stdint.h>

#define NBATCH 16384
#define MB 16
#define NT 256
#define NBLOCKS (NBATCH/MB)
#define WT_BYTE_OFF 2560

typedef float  f32x4 __attribute__((ext_vector_type(4)));
typedef short  s16x8 __attribute__((ext_vector_type(8)));

// ================= compile-time CG (double precision, mirrors validated device math) ==========
constexpr double cfact(int n){ double r=1.0; for(int i=2;i<=n;++i) r*=(double)i; return r; }
constexpr double csqrt_(double x){
  if (x<=0.0) return 0.0;
  double m=x, k=1.0;
  while (m>1.0) { m*=0.25; k*=2.0; }
  while (m<0.25){ m*=4.0;  k*=0.5; }
  double g=0.7;
  for(int i=0;i<14;++i) g = 0.5*(g + m/g);
  return g*k;
}
constexpr double su2d(int j1,int j2,int j3,int m1,int m2,int m3){
  if (m1+m2 != m3) return 0.0;
  double pref = csqrt_((double)(2*j3+1)*cfact(j1+j2-j3)*cfact(j1-j2+j3)*cfact(-j1+j2+j3)/cfact(j1+j2+j3+1));
  pref *= csqrt_(cfact(j3+m3)*cfact(j3-m3)*cfact(j1-m1)*cfact(j1+m1)*cfact(j2-m2)*cfact(j2+m2));
  double s=0.0;
  for (int v=0; v<=j1+j2-j3; ++v){
    int a=j1+j2-j3-v, b=j1-m1-v, c=j2+m2-v, d=j3-j2+m1+v, e=j3-j1-m2+v;
    if (a<0||b<0||c<0||d<0||e<0) continue;
    double t = 1.0/(cfact(v)*cfact(a)*cfact(b)*cfact(c)*cfact(d)*cfact(e));
    s += (v&1)? -t : t;
  }
  return pref*s;
}
struct C2 { double re, im; };
constexpr C2 qvald(int l,int r,int c){
  int m = r - l;
  const double is2 = 0.70710678118654752440;
  double br=0.0, bi=0.0;
  if (m<0){ if (c==l-m) br=is2; else if (c==l+m) bi=-is2; }
  else if (m==0){ if (c==l) br=1.0; }
  else { double sg=(m&1)?-1.0:1.0; if (c==l+m) br=sg*is2; else if (c==l-m) bi=sg*is2; }
  if (l==1){ double nr=bi, ni=-br; br=nr; bi=ni; }   // *(-i)
  else if (l==2){ br=-br; bi=-bi; }                  // *(-i)^2
  return C2{br,bi};
}
constexpr int HP_L1[15]={0,1,2,0,1,1,1,2,2,0,1,1,2,2,2};
constexpr int HP_L2[15]={0,1,2,1,0,1,2,1,2,2,1,2,0,1,2};
constexpr int HP_L3[15]={0,0,0,1,1,1,1,1,1,2,2,2,2,2,2};
constexpr int HP_CGOFF[15]={0,1,10,35,44,53,80,125,170,245,270,315,390,415,490};
constexpr int HP_TSTART[15]={0,1,4,9,12,21,30,39,54,69,74,89,104,129,154};
constexpr int HP_YOFF[15]={0,1,4,1,0,1,4,1,4,4,1,4,0,1,4};

struct CGT { float v[616]; };
constexpr CGT make_cg_part(int p0, int p1){
  CGT T{};
  for (int z=0; z<616; ++z) T.v[z]=0.f;
  for (int p=p0; p<p1; ++p){
    int l1=HP_L1[p], l2=HP_L2[p], l3=HP_L3[p];
    int d1=2*l1+1, d2=2*l2+1, d3=2*l3+1;
    double su[5][5]={};
    for (int i=0;i<d1;++i) for (int k=0;k<d2;++k){
      int n = i+k-l1-l2+l3;
      su[i][k] = (n>=0 && n<d3) ? su2d(l1,l2,l3, i-l1, k-l2, n-l3) : 0.0;
    }
    for (int i1=0;i1<d1;++i1) for (int i2=0;i2<d2;++i2) for (int i3=0;i3<d3;++i3){
      double val=0.0;
      for (int i=0;i<d1;++i) for (int k=0;k<d2;++k){
        int n = i+k-l1-l2+l3;
        if (n<0||n>=d3) continue;
        double c = su[i][k];
        if (c==0.0) continue;
        C2 q1=qvald(l1,i,i1), q2=qvald(l2,k,i2), q3=qvald(l3,n,i3);
        double ar = q1.re*q2.re - q1.im*q2.im;
        double ai = q1.re*q2.im + q1.im*q2.re;
        val += (ar*q3.re + ai*q3.im)*c;    // Re[(q1*q2)*conj(q3)] * su2
      }
      T.v[HP_CGOFF[p] + (i1*d2+i2)*d3 + i3] = (float)val;
    }
  }
  return T;
}
constexpr CGT CG_A = make_cg_part(0,8);
constexpr CGT CG_B = make_cg_part(8,12);
constexpr CGT CG_D = make_cg_part(12,15);
constexpr CGT cg_merge(){
  CGT T{};
  for (int i=0;i<616;++i) T.v[i] = CG_A.v[i] + CG_B.v[i] + CG_D.v[i];
  return T;
}
__device__ __constant__ const CGT CGC = cg_merge();

// packed T descriptor per e: base(10) | d2<<10 (3) | stride<<13 (3) | yoff<<16 (3)
constexpr uint32_t make_td(int e){
  if (e>=179) return 0u;
  int p=0; while (p<14 && e>=HP_TSTART[p+1]) ++p;
  int r = e - HP_TSTART[p];
  int d2 = 2*HP_L2[p]+1, d3 = 2*HP_L3[p]+1;
  int i1 = r/d3, j3 = r - (r/d3)*d3;
  int base = HP_CGOFF[p] + i1*d2*d3 + j3;
  return (uint32_t)base | ((uint32_t)d2<<10) | ((uint32_t)d3<<13) | ((uint32_t)HP_YOFF[p]<<16);
}
struct TDT { uint32_t v[192]; };
constexpr TDT make_tdt(){ TDT t{}; for(int e=0;e<192;++e) t.v[e]=make_td(e); return t; }
__device__ __constant__ const TDT TDC = make_tdt();

// inverse x-permute: output slot o -> source column c (0xFFFF = zero pad)
constexpr uint16_t cmap1(int o){
  if (o<128) return (uint16_t)o;
  if (o<320){ int s=o-128; int i1=s>>6; int u=s&63; return (uint16_t)(128 + u*3 + i1); }
  if (o<480){ int s=o-320; int i1=s>>5; int u=s&31; return (uint16_t)(320 + u*5 + i1); }
  return (uint16_t)0xFFFF;
}
struct CMT { uint16_t v[512]; };
constexpr CMT make_cm(){ CMT t{}; for(int o=0;o<512;++o) t.v[o]=cmap1(o); return t; }
__device__ __constant__ const CMT CMC = make_cm();

// ---------------- weight segments (validated) ----------------
__device__ const int   SEG_WB[15] = {0,16384,24576, 28672,36864,40960,45056,49152,51200,
                                     53248,57344,59392,61440,62464,63488};
__device__ const int   SEG_SH[15] = {7,6,5, 7,6,6,6,5,5, 7,6,6,5,5,5};
__device__ const int   SEG_U0[15] = {0,128,192, 0,128,192,256,320,352, 0,128,192,256,288,320};
__device__ const int   SEG_G[15]  = {0,0,0, 1,1,1,1,1,1, 2,2,2,2,2,2};
__device__ const float SEG_SC[3]  = {0.066815310478f, 0.051031036308f, 0.053300179089f};

// ---------------- bf16 helpers ----------------
__device__ __forceinline__ uint32_t f2bf(float f){
  uint32_t u = __float_as_uint(f);
  return (u + 0x7fffu + ((u>>16)&1u)) >> 16;   // RNE
}
__device__ __forceinline__ float bf2f(uint32_t v){ return __uint_as_float(v << 16); }

// ================= pack_w: weight pack in MFMA-fragment order ==================
// Element (v,u) of segment j stored at (u16 index):
//   WB[j] + (v>>4)*MUL*16 + (u>>5)*512 + (((u>>3)&3)*16 + (v&15))*8 + (u&7)
// => reader lane (ln=v&15, ko=u-octet) loads 16B at base + vt*MUL*16 + kk*512 + lane*8:
//    fully coalesced 1KB per wave Af load (was 256B-strided, 16 lines/inst).
__global__ __launch_bounds__(NT) void pack_w(const float* __restrict__ W0, const float* __restrict__ W1,
                                             const float* __restrict__ W2, float* __restrict__ ws)
{
  int t = blockIdx.x*NT + threadIdx.x;
  uint16_t* wt = (uint16_t*)((char*)ws + WT_BYTE_OFF);
  int j = 0;
  while (j < 14 && t >= SEG_WB[j+1]) ++j;
  int idx = t - SEG_WB[j];
  int sh = SEG_SH[j];
  int v  = idx >> sh, u1 = idx & ((1<<sh)-1);
  int g  = SEG_G[j];
  int N  = (g==0)?128:(g==1)?64:32;
  const float* Wsrc = (g==0)?W0:(g==1)?W1:W2;
  const int vt = v >> 4, ln = v & 15;
  const int kk = u1 >> 5, ko = (u1 >> 3) & 3, s = u1 & 7;
  const int dest = SEG_WB[j] + ((vt << sh) << 4) + kk*512 + (ko*16 + ln)*8 + s;
  wt[dest] = (uint16_t)f2bf(Wsrc[(SEG_U0[j]+u1)*N + v] * SEG_SC[g]);
}

// ---------------- per-group compile-time metadata ----------------
template<int G> struct GM;
template<> struct GM<0>{
  static constexpr int NS=3, D3=1, NMT=2, NI3=1;
  static constexpr int MUL[3]={128,64,32};
  static constexpr int D1[3] ={1,3,5};
  static constexpr int XB[3] ={0,128,320};
  static constexpr int TS[3] ={0,1,4};
  static constexpr int WB[3] ={0,16384,24576};
};
template<> struct GM<1>{
  static constexpr int NS=6, D3=3, NMT=1, NI3=3;
  static constexpr int MUL[6]={128,64,64,64,32,32};
  static constexpr int D1[6] ={1,3,3,3,5,5};
  static constexpr int XB[6] ={0,128,128,128,320,320};
  static constexpr int TS[6] ={9,12,21,30,39,54};
  static constexpr int WB[6] ={28672,36864,40960,45056,49152,51200};
};
template<> struct GM<2>{
  static constexpr int NS=6, D3=5, NMT=1, NI3=3;
  static constexpr int MUL[6]={128,64,64,32,32,32};
  static constexpr int D1[6] ={1,3,3,5,5,5};
  static constexpr int XB[6] ={0,128,128,320,320,320};
  static constexpr int TS[6] ={69,74,89,104,129,154};
  static constexpr int WB[6] ={53248,57344,59392,61440,62464,63488};
};

// one segment: A=Wt (m=v), B=xp (n=batch), K=mul; T-contract into acc
template<int G, int S, int NMT, int NI3>
__device__ __forceinline__ void do_seg(const short* __restrict__ wt,
                                       const uint16_t* __restrict__ xp,
                                       const uint16_t* __restrict__ Tsh,
                                       f32x4 (&acc)[NMT][NI3],
                                       int lane, int ln, int koct, int mt0, int i3base, int ni3)
{
  using M = GM<G>;
  constexpr int MUL = M::MUL[S];
  constexpr int KS  = MUL >> 5;
  constexpr int D1  = M::D1[S];

  // coalesced A-fragment loads: 16B/lane contiguous across the wave
  s16x8 Af[NMT][KS];
  const short* wbase = wt + M::WB[S] + lane*8;
  #pragma unroll
  for (int mt = 0; mt < NMT; ++mt)
    #pragma unroll
    for (int kk = 0; kk < KS; ++kk)
      Af[mt][kk] = *(const s16x8*)(wbase + (mt0+mt)*(MUL*16) + kk*512);

  const int swz = (ln & 7) << 4;
  const int koct2 = koct*2;
  const char* xrow = (const char*)xp + ln*1024;

  #pragma unroll
  for (int i1 = 0; i1 < D1; ++i1){
    s16x8 Bf[KS];
    #pragma unroll
    for (int kk = 0; kk < KS; ++kk){
      const int cb = (M::XB[S] + i1*MUL + kk*32)*2 + koct2;
      Bf[kk] = *(const s16x8*)(xrow + (cb ^ swz));
    }
    f32x4 D[NMT];
    #pragma unroll
    for (int mt = 0; mt < NMT; ++mt){
      D[mt] = (f32x4){0.f,0.f,0.f,0.f};
      #pragma unroll
      for (int kk = 0; kk < KS; ++kk)
        D[mt] = __builtin_amdgcn_mfma_f32_16x16x32_bf16(Af[mt][kk], Bf[kk], D[mt], 0, 0, 0);
    }
    #pragma unroll
    for (int j = 0; j < NI3; ++j){
      if (j < ni3){
        const int e = M::TS[S] + i1*M::D3 + i3base + j;
        const float tv = bf2f(Tsh[e*16 + ln]);
        #pragma unroll
        for (int mt = 0; mt < NMT; ++mt){
          acc[mt][j][0] += tv*D[mt][0];
          acc[mt][j][1] += tv*D[mt][1];
          acc[mt][j][2] += tv*D[mt][2];
          acc[mt][j][3] += tv*D[mt][3];
        }
      }
    }
  }
}

template<int G>
__device__ __forceinline__ void run_group(const short* __restrict__ wt,
                                          float* __restrict__ out, int b0, int tid,
                                          const uint16_t* __restrict__ Tsh,
                                          const uint16_t* __restrict__ xp)
{
  using M = GM<G>;
  const int lane = tid & 63, w = tid >> 6;
  const int ln   = lane & 15;          // A: m-index / B: n-index / D: col (=batch)
  const int koct = (lane >> 4) * 8;    // k-octet
  constexpr int NMT = M::NMT, NI3 = M::NI3;

  int mt0, i3base, ni3;
  if constexpr (G == 0){ mt0 = 2*w; i3base = 0; ni3 = 1; }
  else if constexpr (G == 1){ mt0 = w; i3base = 0; ni3 = 3; }
  else { mt0 = w >> 1; i3base = (w & 1)*3; ni3 = (w & 1) ? 2 : 3; }

  f32x4 acc[NMT][NI3];
  #pragma unroll
  for (int a = 0; a < NMT; ++a)
    #pragma unroll
    for (int b = 0; b < NI3; ++b) acc[a][b] = (f32x4){0.f,0.f,0.f,0.f};

  do_seg<G,0,NMT,NI3>(wt, xp, Tsh, acc, lane, ln, koct, mt0, i3base, ni3);
  do_seg<G,1,NMT,NI3>(wt, xp, Tsh, acc, lane, ln, koct, mt0, i3base, ni3);
  do_seg<G,2,NMT,NI3>(wt, xp, Tsh, acc, lane, ln, koct, mt0, i3base, ni3);
  if constexpr (M::NS > 3){
    do_seg<G,(M::NS>3)?3:0,NMT,NI3>(wt, xp, Tsh, acc, lane, ln, koct, mt0, i3base, ni3);
    do_seg<G,(M::NS>4)?4:0,NMT,NI3>(wt, xp, Tsh, acc, lane, ln, koct, mt0, i3base, ni3);
    do_seg<G,(M::NS>5)?5:0,NMT,NI3>(wt, xp, Tsh, acc, lane, ln, koct, mt0, i3base, ni3);
  }

  // ---- stores: D col=lane&15=batch, rows=(lane>>4)*4+r = v (r3-verified) ----
  const int rq = (lane >> 4) * 4;
  float* orow = out + (size_t)(b0 + ln)*480;
  if constexpr (G == 0){
    #pragma unroll
    for (int mt = 0; mt < NMT; ++mt){
      const int vb = (mt0+mt)*16 + rq;
      float4 st = make_float4(acc[mt][0][0], acc[mt][0][1], acc[mt][0][2], acc[mt][0][3]);
      *(float4*)(orow + vb) = st;            // cols v..v+3, 16B aligned
    }
  } else if constexpr (G == 1){
    const int vb = mt0*16 + rq;
    float buf[12];
    #pragma unroll
    for (int r = 0; r < 4; ++r)
      #pragma unroll
      for (int j = 0; j < 3; ++j) buf[r*3+j] = acc[0][j][r];
    float* p = orow + 128 + vb*3;            // 128+12k -> 16B aligned
    *(float4*)(p)   = make_float4(buf[0],buf[1],buf[2],buf[3]);
    *(float4*)(p+4) = make_float4(buf[4],buf[5],buf[6],buf[7]);
    *(float4*)(p+8) = make_float4(buf[8],buf[9],buf[10],buf[11]);
  } else {
    const int vb = mt0*16 + rq;
    #pragma unroll
    for (int r = 0; r < 4; ++r)
      #pragma unroll
      for (int j = 0; j < 3; ++j)
        if (j < ni3)
          orow[320 + (vb+r)*5 + i3base + j] = acc[0][j][r];
  }
}

// ================= fused: stage x/y -> build xp/T in LDS -> MFMA -> out ===========
__global__ __launch_bounds__(NT) void tp_fused(const float* __restrict__ x,
                                               const float* __restrict__ y,
                                               const float* __restrict__ ws,
                                               float* __restrict__ out)
{
  __shared__ __align__(16) uint16_t xs[MB*480];      // 15360 B  bf16 raw x slab
  __shared__ __align__(16) uint16_t xp[MB*512];      // 16384 B  swizzled permuted rows
  __shared__ __align__(16) uint16_t Tsh[192*16];     //  6144 B  T[e][b]
  __shared__ __align__(16) float    ysm[MB*9];       //   576 B
  __shared__ __align__(16) uint16_t cml[512];        //  1024 B  permute map
  // total ~39.5 KB -> 4 blocks/CU (matches VGPR cap of 16 waves/CU)

  const int tid = threadIdx.x;
  const int b0 = blockIdx.x * MB;
  const short* wt = (const short*)((const char*)ws + WT_BYTE_OFF);

  // ---- stage x (f32 -> bf16, fully coalesced float4), y, permute map ----
  {
    const float4* src = (const float4*)(x + (size_t)b0*480);
    #pragma unroll
    for (int it = 0; it < 8; ++it){
      int i = it*NT + tid;
      if (i < 1920){
        float4 v = src[i];
        uint16_t p[4] = {(uint16_t)f2bf(v.x),(uint16_t)f2bf(v.y),
                         (uint16_t)f2bf(v.z),(uint16_t)f2bf(v.w)};
        *(uint2*)(&xs[i*4]) = *(const uint2*)p;
      }
    }
  }
  if (tid < 144) ysm[tid] = y[(size_t)b0*9 + tid];
  else if (tid >= 192) ((uint4*)cml)[tid-192] = ((const uint4*)CMC.v)[tid-192];
  __syncthreads();

  // ---- build xp (swizzled) + Tsh, all in LDS ----
  #pragma unroll
  for (int it = 0; it < 4; ++it){
    const int chunk = it*NT + tid;
    const int b = chunk >> 6, c16 = chunk & 63;      // wave = one batch row
    uint16_t vals[8];
    #pragma unroll
    for (int jj = 0; jj < 8; ++jj){
      const uint16_t c = cml[c16*8 + jj];
      vals[jj] = (c == 0xFFFFu) ? (uint16_t)0 : xs[b*480 + c];
    }
    *(uint4*)((char*)xp + b*1024 + ((c16*16) ^ ((b&7)<<4))) = *(const uint4*)vals;
  }
  if (tid < 179){
    const uint32_t td = TDC.v[tid];
    const int base = td & 1023, d2 = (td>>10)&7, str = (td>>13)&7, yoff = (td>>16)&7;
    uint16_t tv[16];
    #pragma unroll
    for (int b = 0; b < 16; ++b){
      float t = 0.f;
      for (int i2 = 0; i2 < d2; ++i2) t += CGC.v[base + i2*str] * ysm[b*9 + yoff + i2];
      tv[b] = (uint16_t)f2bf(t);
    }
    *(uint4*)(&Tsh[tid*16])     = *(const uint4*)&tv[0];
    *(uint4*)(&Tsh[tid*16 + 8]) = *(const uint4*)&tv[8];
  }
  __syncthreads();

  // ---- 3 groups, no further barriers (xp/Tsh read-only from here) ----
  run_group<0>(wt, out, b0, tid, Tsh, xp);
  run_group<1>(wt, out, b0, tid, Tsh, xp);
  run_group<2>(wt, out, b0, tid, Tsh, xp);
}

extern "C" void kernel_launch(void* const* d_in, const int* in_sizes, int n_in,
                              void* d_out, int out_size, void* d_ws, size_t ws_size,
                              hipStream_t stream)
{
  const float* x  = (const float*)d_in[0];
  const float* y  = (const float*)d_in[1];
  const float* W0 = (const float*)d_in[2];
  const float* W1 = (const float*)d_in[3];
  const float* W2 = (const float*)d_in[4];
  float* out = (float*)d_out;
  float* ws  = (float*)d_ws;   // bf16 Wt (fragment-ordered) at +2560 (CG is compile-time)

  hipLaunchKernelGGL(pack_w, dim3(252), dim3(NT), 0, stream, W0, W1, W2, ws);
  hipLaunchKernelGGL(tp_fused, dim3(NBLOCKS), dim3(NT), 0, stream, x, y, ws, out);
}